// Round 12
// baseline (462.955 us; speedup 1.0000x reference)
//
#include <hip/hip_runtime.h>
#include <math.h>

#define EPS 1e-5f
#define PS 8  // pool slices per group
#define SW(row) (((row) & 7) << 4)   // XOR swizzle, 16B granularity

typedef __attribute__((ext_vector_type(8))) short short8;
typedef __attribute__((ext_vector_type(4))) float f32x4;

__device__ __forceinline__ float bf2f(unsigned short u) {
  union { unsigned i; float f; } c; c.i = ((unsigned)u) << 16; return c.f;
}
__device__ __forceinline__ float bflo(unsigned u) {
  union { unsigned i; float f; } c; c.i = u << 16; return c.f;
}
__device__ __forceinline__ float bfhi(unsigned u) {
  union { unsigned i; float f; } c; c.i = u & 0xFFFF0000u; return c.f;
}
__device__ __forceinline__ unsigned short f2bf(float f) {
  union { float f; unsigned i; } c; c.f = f;
  unsigned r = c.i + 0x7FFF + ((c.i >> 16) & 1);
  return (unsigned short)(r >> 16);
}

// ---------------------------------------------------------------------------
// Embed GEMM (K=128), LDS-staged: hb = relu(x_f32 @ W^T + bias) bf16 (+score).
// BM=64, 4 waves 2x2 (wave tile 32x64). XOR-swizzled LDS.
// ---------------------------------------------------------------------------
template <bool SCORE>
__global__ __launch_bounds__(256, 2) void embed_gemm(
    const float* __restrict__ X,      // x [M][128] fp32
    const ushort* __restrict__ W,     // [128][128] bf16
    const float* __restrict__ bias,
    const float* __restrict__ Wsc, const float* __restrict__ bsc,
    ushort* __restrict__ hb, float* __restrict__ scores, int M) {
  __shared__ __align__(16) ushort As[64 * 128];    // 16 KB, row 256 B
  __shared__ __align__(16) ushort Ws[128 * 128];   // 32 KB, row 256 B
  __shared__ float lds3[64][2];

  const int t = threadIdx.x;
  const int lane = t & 63;
  const int w = t >> 6;
  const int wm = w >> 1, wn = w & 1;
  const int m0 = blockIdx.x * 64;
  const int l15 = lane & 15, l16 = lane >> 4;

  short8 ar[4], wr_[8];
#pragma unroll
  for (int it = 0; it < 4; ++it) {
    int chunk = it * 256 + t;
    int row = chunk >> 4;
    int b16 = chunk & 15;
    int grow = m0 + row; if (grow >= M) grow = M - 1;
    const float* xr = X + (size_t)grow * 128 + b16 * 8;
    float4 f0 = *(const float4*)xr;
    float4 f1 = *(const float4*)(xr + 4);
    short8 v;
    v[0] = (short)f2bf(f0.x); v[1] = (short)f2bf(f0.y);
    v[2] = (short)f2bf(f0.z); v[3] = (short)f2bf(f0.w);
    v[4] = (short)f2bf(f1.x); v[5] = (short)f2bf(f1.y);
    v[6] = (short)f2bf(f1.z); v[7] = (short)f2bf(f1.w);
    ar[it] = v;
  }
#pragma unroll
  for (int it = 0; it < 8; ++it) {
    int chunk = it * 256 + t;
    int row = chunk >> 4;
    int b16 = chunk & 15;
    wr_[it] = *(const short8*)(W + (size_t)row * 128 + b16 * 8);
  }
#pragma unroll
  for (int it = 0; it < 4; ++it) {
    int chunk = it * 256 + t;
    int row = chunk >> 4, b = (chunk & 15) * 16;
    *(short8*)((char*)As + row * 256 + (b ^ SW(row))) = ar[it];
  }
#pragma unroll
  for (int it = 0; it < 8; ++it) {
    int chunk = it * 256 + t;
    int row = chunk >> 4, b = (chunk & 15) * 16;
    *(short8*)((char*)Ws + row * 256 + (b ^ SW(row))) = wr_[it];
  }
  __syncthreads();

  f32x4 acc[2][4];
#pragma unroll
  for (int i = 0; i < 2; ++i)
#pragma unroll
    for (int j = 0; j < 4; ++j) acc[i][j] = (f32x4){0.f, 0.f, 0.f, 0.f};

#pragma unroll
  for (int kk = 0; kk < 4; ++kk) {
    int cb = kk * 64 + l16 * 16;
    short8 a[2], b[4];
#pragma unroll
    for (int i = 0; i < 2; ++i) {
      int row = wm * 32 + i * 16 + l15;
      a[i] = *(const short8*)((const char*)As + row * 256 + (cb ^ SW(row)));
    }
#pragma unroll
    for (int j = 0; j < 4; ++j) {
      int row = wn * 64 + j * 16 + l15;
      b[j] = *(const short8*)((const char*)Ws + row * 256 + (cb ^ SW(row)));
    }
#pragma unroll
    for (int i = 0; i < 2; ++i)
#pragma unroll
      for (int j = 0; j < 4; ++j)
        acc[i][j] = __builtin_amdgcn_mfma_f32_16x16x32_bf16(a[i], b[j], acc[i][j], 0, 0, 0);
  }

#pragma unroll
  for (int i = 0; i < 2; ++i)
#pragma unroll
    for (int r = 0; r < 4; ++r) {
      int row = m0 + wm * 32 + i * 16 + l16 * 4 + r;
      bool valid = row < M;
      float psc = 0.f;
#pragma unroll
      for (int j = 0; j < 4; ++j) {
        int colw = wn * 64 + j * 16 + l15;
        float v = acc[i][j][r] + bias[colw];
        v = fmaxf(v, 0.f);
        if (valid) hb[(size_t)row * 128 + colw] = f2bf(v);
        if (SCORE) psc += v * Wsc[colw];
      }
      if (SCORE) {
#pragma unroll
        for (int mm = 1; mm <= 8; mm <<= 1) psc += __shfl_xor(psc, mm, 64);
        if (l15 == 0) lds3[wm * 32 + i * 16 + l16 * 4 + r][wn] = psc;
      }
    }
  if (SCORE) {
    __syncthreads();
    if (wn == 0 && l15 == 0) {
#pragma unroll
      for (int i = 0; i < 2; ++i)
#pragma unroll
        for (int r = 0; r < 4; ++r) {
          int rl = wm * 32 + i * 16 + l16 * 4 + r;
          int row = blockIdx.x * 64 + rl;
          if (row < M) scores[row] = lds3[rl][0] + lds3[rl][1] + bsc[0];
        }
    }
  }
}

// ---------------------------------------------------------------------------
// FUSED layer: per block of 64 rows:
//   Phase 1: edge aggregation (4 nodes/wave quarters, x4-unrolled gather)
//            u,v written straight into swizzled LDS A-tiles (bf16).
//   Phase 2: stage h rows into LDS.
//   Phase 3: GEMM K=384 as 6 W-substages (128x64 each) x 2 ksteps,
//            A thirds = [As_h | As_u | As_v].
//   Epilogue: bias+LN+relu+residual(hin) -> hout (+ next scores).
// Ping-pong h/scores buffers across layers (blocks write hout while others
// still gather hin). LDS: 3x16 + 16 = 64 KB -> 2 blocks/CU.
// ---------------------------------------------------------------------------
template <bool SCORE>
__global__ __launch_bounds__(256, 2) void fused_layer(
    const int* __restrict__ indptr, const int* __restrict__ ssrc,
    const float* __restrict__ sc_in, const ushort* __restrict__ hin,
    const ushort* __restrict__ W,     // Wbig [128][384]
    const float* __restrict__ bias,
    const float* __restrict__ gamma, const float* __restrict__ beta,
    const float* __restrict__ Wsc, const float* __restrict__ bsc,
    ushort* __restrict__ hout, float* __restrict__ sc_out, int M) {
  __shared__ __align__(16) ushort As_h[64 * 128];  // 16 KB, row 256 B
  __shared__ __align__(16) ushort As_u[64 * 128];  // 16 KB
  __shared__ __align__(16) ushort As_v[64 * 128];  // 16 KB
  __shared__ __align__(16) ushort Ws_[128 * 64];   // 16 KB, row 128 B
  __shared__ float lds1[64][2];
  __shared__ float lds2[64][2];
  __shared__ float lds3[64][2];

  const int t = threadIdx.x;
  const int lane = t & 63;
  const int w4 = t >> 6;
  const int wm = w4 >> 1, wn = w4 & 1;
  const int m0 = blockIdx.x * 64;
  const int l15 = lane & 15, l16 = lane >> 4;
  const int q = lane & 15;          // lane within quarter
  const int qbase = lane & 48;      // quarter start lane (for shfl)
  const int qsel = lane >> 4;       // quarter index 0..3

  // ---- Phase 1: aggregation for 64 rows (4 rounds x 4 nodes/wave) ----
#pragma unroll 1
  for (int round = 0; round < 4; ++round) {
    int rl = w4 * 16 + round * 4 + qsel;    // local row 0..63
    int node = m0 + rl;
    int beg = 0, end = 0;
    float si = 0.f;
    if (node < M) { beg = indptr[node]; end = indptr[node + 1]; si = sc_in[node]; }
    float u0 = 0.f, u1 = 0.f, u2 = 0.f, u3 = 0.f;
    float u4 = 0.f, u5 = 0.f, u6 = 0.f, u7 = 0.f;
    float t0 = 0.f, t1 = 0.f, t2 = 0.f, t3 = 0.f;
    float t4 = 0.f, t5 = 0.f, t6 = 0.f, t7 = 0.f;
    for (int ebase = beg; ebase < end; ebase += 16) {
      int cnt = min(16, end - ebase);
      int sv = 0;
      float al = 0.f;
      if (q < cnt) {
        sv = ssrc[ebase + q];
        al = 1.f / (1.f + __expf(si - sc_in[sv]));  // sigmoid(s_src - s_dst)
      }
      int e = 0;
      for (; e + 4 <= cnt; e += 4) {
        int s0 = __shfl(sv, qbase + e, 64),     s1 = __shfl(sv, qbase + e + 1, 64);
        int s2 = __shfl(sv, qbase + e + 2, 64), s3 = __shfl(sv, qbase + e + 3, 64);
        float a0 = __shfl(al, qbase + e, 64),     a1 = __shfl(al, qbase + e + 1, 64);
        float a2 = __shfl(al, qbase + e + 2, 64), a3 = __shfl(al, qbase + e + 3, 64);
        uint4 v0 = *(const uint4*)(hin + (size_t)s0 * 128 + q * 8);
        uint4 v1 = *(const uint4*)(hin + (size_t)s1 * 128 + q * 8);
        uint4 v2 = *(const uint4*)(hin + (size_t)s2 * 128 + q * 8);
        uint4 v3 = *(const uint4*)(hin + (size_t)s3 * 128 + q * 8);
        float f;
#define ACC8(V, A)                                              \
        f = bflo(V.x); u0 = fmaf(A, f, u0); t0 += f;            \
        f = bfhi(V.x); u1 = fmaf(A, f, u1); t1 += f;            \
        f = bflo(V.y); u2 = fmaf(A, f, u2); t2 += f;            \
        f = bfhi(V.y); u3 = fmaf(A, f, u3); t3 += f;            \
        f = bflo(V.z); u4 = fmaf(A, f, u4); t4 += f;            \
        f = bfhi(V.z); u5 = fmaf(A, f, u5); t5 += f;            \
        f = bflo(V.w); u6 = fmaf(A, f, u6); t6 += f;            \
        f = bfhi(V.w); u7 = fmaf(A, f, u7); t7 += f;
        ACC8(v0, a0)
        ACC8(v1, a1)
        ACC8(v2, a2)
        ACC8(v3, a3)
      }
      for (; e < cnt; ++e) {
        int s_e = __shfl(sv, qbase + e, 64);
        float a_e = __shfl(al, qbase + e, 64);
        uint4 vv = *(const uint4*)(hin + (size_t)s_e * 128 + q * 8);
        float f;
        ACC8(vv, a_e)
#undef ACC8
      }
    }
    short8 pu, pv;
    pu[0] = (short)f2bf(u0); pu[1] = (short)f2bf(u1);
    pu[2] = (short)f2bf(u2); pu[3] = (short)f2bf(u3);
    pu[4] = (short)f2bf(u4); pu[5] = (short)f2bf(u5);
    pu[6] = (short)f2bf(u6); pu[7] = (short)f2bf(u7);
    pv[0] = (short)f2bf(t0 - u0); pv[1] = (short)f2bf(t1 - u1);
    pv[2] = (short)f2bf(t2 - u2); pv[3] = (short)f2bf(t3 - u3);
    pv[4] = (short)f2bf(t4 - u4); pv[5] = (short)f2bf(t5 - u5);
    pv[6] = (short)f2bf(t6 - u6); pv[7] = (short)f2bf(t7 - u7);
    *(short8*)((char*)As_u + rl * 256 + ((q * 16) ^ SW(rl))) = pu;
    *(short8*)((char*)As_v + rl * 256 + ((q * 16) ^ SW(rl))) = pv;
  }

  // ---- Phase 2: stage h rows (global -> reg -> LDS) ----
  {
    short8 ar[4];
#pragma unroll
    for (int it = 0; it < 4; ++it) {
      int chunk = it * 256 + t;
      int row = chunk >> 4;
      int b16 = chunk & 15;
      int grow = m0 + row; if (grow >= M) grow = M - 1;
      ar[it] = *(const short8*)(hin + (size_t)grow * 128 + b16 * 8);
    }
#pragma unroll
    for (int it = 0; it < 4; ++it) {
      int chunk = it * 256 + t;
      int row = chunk >> 4, b = (chunk & 15) * 16;
      *(short8*)((char*)As_h + row * 256 + (b ^ SW(row))) = ar[it];
    }
  }
  __syncthreads();

  f32x4 acc[2][4];
#pragma unroll
  for (int i = 0; i < 2; ++i)
#pragma unroll
    for (int j = 0; j < 4; ++j) acc[i][j] = (f32x4){0.f, 0.f, 0.f, 0.f};

  // ---- Phase 3: 6 W-substages (128 rows x 64 kelems) x 2 ksteps each ----
#pragma unroll 1
  for (int s = 0; s < 6; ++s) {
    short8 wr_[4];
#pragma unroll
    for (int it = 0; it < 4; ++it) {
      int chunk = it * 256 + t;        // 1024 chunks: 128 rows x 8 chunks
      int row = chunk >> 3;
      int c8 = chunk & 7;
      wr_[it] = *(const short8*)(W + (size_t)row * 384 + s * 64 + c8 * 8);
    }
    __syncthreads();  // previous substage's readers done
#pragma unroll
    for (int it = 0; it < 4; ++it) {
      int chunk = it * 256 + t;
      int row = chunk >> 3, b = (chunk & 7) * 16;
      *(short8*)((char*)Ws_ + row * 128 + (b ^ SW(row))) = wr_[it];
    }
    __syncthreads();
    const ushort* Asrc = (s < 2) ? As_h : (s < 4) ? As_u : As_v;
#pragma unroll
    for (int kk2 = 0; kk2 < 2; ++kk2) {
      int cbA = (s & 1) * 128 + kk2 * 64 + l16 * 16;
      int cbW = kk2 * 64 + l16 * 16;
      short8 a[2], b[4];
#pragma unroll
      for (int i = 0; i < 2; ++i) {
        int row = wm * 32 + i * 16 + l15;
        a[i] = *(const short8*)((const char*)Asrc + row * 256 + (cbA ^ SW(row)));
      }
#pragma unroll
      for (int j = 0; j < 4; ++j) {
        int row = wn * 64 + j * 16 + l15;
        b[j] = *(const short8*)((const char*)Ws_ + row * 128 + (cbW ^ SW(row)));
      }
#pragma unroll
      for (int i = 0; i < 2; ++i)
#pragma unroll
        for (int j = 0; j < 4; ++j)
          acc[i][j] = __builtin_amdgcn_mfma_f32_16x16x32_bf16(a[i], b[j], acc[i][j], 0, 0, 0);
    }
  }

  // ---- epilogue: bias + LN stats (pass 1) ----
#pragma unroll
  for (int i = 0; i < 2; ++i)
#pragma unroll
    for (int r = 0; r < 4; ++r) {
      float p1 = 0.f, p2 = 0.f;
#pragma unroll
      for (int j = 0; j < 4; ++j) {
        int colw = wn * 64 + j * 16 + l15;
        float v = acc[i][j][r] + bias[colw];
        acc[i][j][r] = v;
        p1 += v;
        p2 += v * v;
      }
#pragma unroll
      for (int mm = 1; mm <= 8; mm <<= 1) {
        p1 += __shfl_xor(p1, mm, 64);
        p2 += __shfl_xor(p2, mm, 64);
      }
      if (l15 == 0) {
        int rl = wm * 32 + i * 16 + l16 * 4 + r;
        lds1[rl][wn] = p1;
        lds2[rl][wn] = p2;
      }
    }
  __syncthreads();
  // ---- pass 2: normalize + relu + residual(hin) + store to hout ----
#pragma unroll
  for (int i = 0; i < 2; ++i)
#pragma unroll
    for (int r = 0; r < 4; ++r) {
      int rl = wm * 32 + i * 16 + l16 * 4 + r;
      int row = m0 + rl;
      bool valid = row < M;
      float s1 = lds1[rl][0] + lds1[rl][1];
      float s2 = lds2[rl][0] + lds2[rl][1];
      float mu = s1 * (1.f / 128.f);
      float var = s2 * (1.f / 128.f) - mu * mu;
      float rs = rsqrtf(var + EPS);
      float psc = 0.f;
#pragma unroll
      for (int j = 0; j < 4; ++j) {
        int colw = wn * 64 + j * 16 + l15;
        float v = acc[i][j][r];
        float o = (v - mu) * rs * gamma[colw] + beta[colw];
        o = fmaxf(o, 0.f);
        float res = o;
        if (valid) {
          res = o + bf2f(hin[(size_t)row * 128 + colw]);
          hout[(size_t)row * 128 + colw] = f2bf(res);
        }
        if (SCORE) psc += res * Wsc[colw];
      }
      if (SCORE) {
#pragma unroll
        for (int mm = 1; mm <= 8; mm <<= 1) psc += __shfl_xor(psc, mm, 64);
        if (l15 == 0) lds3[rl][wn] = psc;
      }
    }
  if (SCORE) {
    __syncthreads();
    if (wn == 0 && l15 == 0) {
#pragma unroll
      for (int i = 0; i < 2; ++i)
#pragma unroll
        for (int r = 0; r < 4; ++r) {
          int rl = wm * 32 + i * 16 + l16 * 4 + r;
          int row = m0 + rl;
          if (row < M) sc_out[row] = lds3[rl][0] + lds3[rl][1] + bsc[0];
        }
    }
  }
}

// ---------------------------------------------------------------------------
// Weight precompute: Wbig[l][:, p*128:(p+1)*128] = Wcomb[l][:,p-part] @ Wp[l]
// ---------------------------------------------------------------------------
__global__ __launch_bounds__(256) void wpre_kernel(
    const float* __restrict__ Wcomb, const float* __restrict__ Wself,
    const float* __restrict__ Wfwd, const float* __restrict__ Wbwd,
    ushort* __restrict__ Wbig) {
  const int l = blockIdx.x / 3, p = blockIdx.x % 3;
  const float* Wc = Wcomb + (size_t)l * 128 * 384;
  const float* Wp = (p == 0 ? Wself : (p == 1 ? Wfwd : Wbwd)) + (size_t)l * 128 * 128;
  __shared__ float Bs[128][132];
  const int t = threadIdx.x;
  for (int i = t; i < 16384; i += 256) Bs[i >> 7][i & 127] = Wp[i];
  __syncthreads();
  const int r = t >> 1;
  const int c0 = (t & 1) * 64;
  float acc[64];
#pragma unroll
  for (int c = 0; c < 64; ++c) acc[c] = 0.f;
  for (int k = 0; k < 128; ++k) {
    float a = Wc[(size_t)r * 384 + p * 128 + k];
#pragma unroll
    for (int c4 = 0; c4 < 16; ++c4) {
      float4 b4 = *(const float4*)&Bs[k][c0 + c4 * 4];
      acc[c4 * 4 + 0] = fmaf(a, b4.x, acc[c4 * 4 + 0]);
      acc[c4 * 4 + 1] = fmaf(a, b4.y, acc[c4 * 4 + 1]);
      acc[c4 * 4 + 2] = fmaf(a, b4.z, acc[c4 * 4 + 2]);
      acc[c4 * 4 + 3] = fmaf(a, b4.w, acc[c4 * 4 + 3]);
    }
  }
  ushort* o = Wbig + (size_t)l * 128 * 384 + (size_t)r * 384 + p * 128 + c0;
#pragma unroll
  for (int c = 0; c < 64; ++c) o[c] = f2bf(acc[c]);
}

// bias_c[l][c] = bcomb[l][c] + sum_k Wcomb[l][c][k] * bself[l][k]
__global__ void bpre_kernel(const float* __restrict__ Wcomb, const float* __restrict__ bself,
                            const float* __restrict__ bcomb, float* __restrict__ biasc, int L) {
  int idx = blockIdx.x * 128 + threadIdx.x;
  if (idx >= L * 128) return;
  int l = idx >> 7;
  const float* Wc = Wcomb + (size_t)l * 128 * 384 + (size_t)(idx & 127) * 384;
  const float* bs = bself + (size_t)l * 128;
  float acc = bcomb[idx];
  for (int k = 0; k < 128; ++k) acc = fmaf(Wc[k], bs[k], acc);
  biasc[idx] = acc;
}

// fp32 -> bf16 (n4 float4 groups)
__global__ void f2b_kernel(const float* __restrict__ in, ushort* __restrict__ out, int n4) {
  int i = blockIdx.x * 256 + threadIdx.x;
  if (i < n4) {
    float4 v = ((const float4*)in)[i];
    ushort4 o;
    o.x = f2bf(v.x); o.y = f2bf(v.y); o.z = f2bf(v.z); o.w = f2bf(v.w);
    ((ushort4*)out)[i] = o;
  }
}

// ---------------------------------------------------------------------------
// CSR build: histogram -> scan -> scatter (counting sort by dst)
// ---------------------------------------------------------------------------
__global__ void hist_kernel(const int* __restrict__ dst, int* __restrict__ counts, int E) {
  int e = blockIdx.x * 256 + threadIdx.x;
  if (e < E) atomicAdd(&counts[dst[e]], 1);
}

__global__ __launch_bounds__(256) void scan1_kernel(
    const int* __restrict__ c, int* __restrict__ ex, int* __restrict__ partials, int n) {
  __shared__ int sd[256];
  int t = threadIdx.x, b = blockIdx.x;
  int base = b * 1024 + t * 4;
  int v0 = (base + 0 < n) ? c[base + 0] : 0;
  int v1 = (base + 1 < n) ? c[base + 1] : 0;
  int v2 = (base + 2 < n) ? c[base + 2] : 0;
  int v3 = (base + 3 < n) ? c[base + 3] : 0;
  int tot = v0 + v1 + v2 + v3;
  sd[t] = tot;
  __syncthreads();
  for (int off = 1; off < 256; off <<= 1) {
    int x = (t >= off) ? sd[t - off] : 0;
    __syncthreads();
    sd[t] += x;
    __syncthreads();
  }
  int p = sd[t] - tot;
  if (base + 0 < n) ex[base + 0] = p;
  if (base + 1 < n) ex[base + 1] = p + v0;
  if (base + 2 < n) ex[base + 2] = p + v0 + v1;
  if (base + 3 < n) ex[base + 3] = p + v0 + v1 + v2;
  if (t == 255) partials[b] = sd[255];
}

__global__ __launch_bounds__(256) void scan2_kernel(int* __restrict__ partials, int nb) {
  __shared__ int sd[256];
  int t = threadIdx.x;
  int v = (t < nb) ? partials[t] : 0;
  sd[t] = v;
  __syncthreads();
  for (int off = 1; off < 256; off <<= 1) {
    int x = (t >= off) ? sd[t - off] : 0;
    __syncthreads();
    sd[t] += x;
    __syncthreads();
  }
  if (t < nb) partials[t] = sd[t] - v;
}

__global__ void scan3_kernel(const int* __restrict__ ex, const int* __restrict__ partials,
                             int* __restrict__ indptr, int* __restrict__ cursor,
                             int n, int E) {
  int i = blockIdx.x * 256 + threadIdx.x;
  if (i < n) {
    int v = ex[i] + partials[i >> 10];
    indptr[i] = v;
    cursor[i] = v;
  }
  if (i == 0) indptr[n] = E;
}

__global__ void scatter_kernel(const int* __restrict__ ei, int* __restrict__ cursor,
                               int* __restrict__ ssrc, int E) {
  int e = blockIdx.x * 256 + threadIdx.x;
  if (e >= E) return;
  int s = ei[e];
  int d = ei[E + e];
  int pos = atomicAdd(&cursor[d], 1);
  ssrc[pos] = s;
}

// ---------------------------------------------------------------------------
// Global mean pool over hb (bf16 state; batch sorted): two-stage, no atomics.
// ---------------------------------------------------------------------------
__global__ __launch_bounds__(128) void pool_stage_kernel(
    const ushort* __restrict__ hb, const int* __restrict__ batch,
    float* __restrict__ partial, int M) {
  int g = blockIdx.x, s = blockIdx.y, d = threadIdx.x;
  int lo = 0, hi = M;
  while (lo < hi) { int mid = (lo + hi) >> 1; if (batch[mid] < g) lo = mid + 1; else hi = mid; }
  int b0 = lo;
  hi = M;
  while (lo < hi) { int mid = (lo + hi) >> 1; if (batch[mid] <= g) lo = mid + 1; else hi = mid; }
  int b1 = lo;
  int len = b1 - b0;
  int chunk = (len + PS - 1) / PS;
  int r0 = b0 + s * chunk;
  int r1 = min(b1, r0 + chunk);
  float acc = 0.f;
  for (int i = r0; i < r1; ++i) acc += bf2f(hb[(size_t)i * 128 + d]);
  partial[((size_t)g * PS + s) * 128 + d] = acc;
}

__global__ void pool_final_kernel(const float* __restrict__ partial,
                                  const int* __restrict__ batch,
                                  float* __restrict__ out, int M, int G) {
  int idx = blockIdx.x * 256 + threadIdx.x;
  if (idx >= G * 128) return;
  int g = idx >> 7, d = idx & 127;
  float acc = 0.f;
#pragma unroll
  for (int s = 0; s < PS; ++s) acc += partial[((size_t)g * PS + s) * 128 + d];
  int lo = 0, hi = M;
  while (lo < hi) { int mid = (lo + hi) >> 1; if (batch[mid] < g) lo = mid + 1; else hi = mid; }
  int b0 = lo;
  hi = M;
  while (lo < hi) { int mid = (lo + hi) >> 1; if (batch[mid] <= g) lo = mid + 1; else hi = mid; }
  int c = lo - b0;
  out[idx] = acc / (float)(c > 0 ? c : 1);
}

// ---------------------------------------------------------------------------
extern "C" void kernel_launch(void* const* d_in, const int* in_sizes, int n_in,
                              void* d_out, int out_size, void* d_ws, size_t ws_size,
                              hipStream_t stream) {
  const float* x      = (const float*)d_in[0];
  const int*   ei     = (const int*)d_in[1];
  const int*   batch  = (const int*)d_in[2];
  const float* Wemb   = (const float*)d_in[3];
  const float* bemb   = (const float*)d_in[4];
  const float* Wscore = (const float*)d_in[5];
  const float* bscore = (const float*)d_in[6];
  const float* Wfwd   = (const float*)d_in[7];
  const float* Wbwd   = (const float*)d_in[8];
  const float* Wself  = (const float*)d_in[9];
  const float* bself  = (const float*)d_in[10];
  const float* Wcomb  = (const float*)d_in[11];
  const float* bcomb  = (const float*)d_in[12];
  const float* gamma  = (const float*)d_in[13];
  const float* beta   = (const float*)d_in[14];

  const int N = in_sizes[0] / 128;
  const int E = in_sizes[1] / 2;
  const int L = in_sizes[5] / 128;
  const int G = out_size / 128;
  float* out = (float*)d_out;

  char* p = (char*)d_ws;
  auto alloc = [&](size_t bytes) -> char* {
    char* r = p;
    p += (bytes + 255) & ~(size_t)255;
    return r;
  };
  ushort* hb0    = (ushort*)alloc((size_t)N * 128 * 2);   // ping-pong bf16 state
  ushort* hb1    = (ushort*)alloc((size_t)N * 128 * 2);
  float*  sc0    = (float*)alloc((size_t)N * 4);          // ping-pong scores
  float*  sc1    = (float*)alloc((size_t)N * 4);
  ushort* Wemb_b = (ushort*)alloc(16384 * 2);
  ushort* Wbig   = (ushort*)alloc((size_t)L * 128 * 384 * 2);
  float*  biasc  = (float*)alloc((size_t)L * 128 * 4);
  int* counts    = (int*)alloc((size_t)N * 4);
  int* ex        = (int*)alloc((size_t)N * 4);
  int* partials  = (int*)alloc(1024);
  int* indptr    = (int*)alloc((size_t)(N + 1) * 4);
  int* cursor    = (int*)alloc((size_t)N * 4);
  int* ssrc      = (int*)alloc((size_t)E * 4);
  float* pool_p  = (float*)alloc((size_t)G * PS * 128 * 4);

  ushort* hbuf[2] = { hb0, hb1 };
  float*  sbuf[2] = { sc0, sc1 };

  const int gb = (N + 63) / 64;

  // 0. precompute: conversions + combined weights
  f2b_kernel<<<16, 256, 0, stream>>>(Wemb, Wemb_b, 4096);
  wpre_kernel<<<3 * L, 256, 0, stream>>>(Wcomb, Wself, Wfwd, Wbwd, Wbig);
  bpre_kernel<<<L, 128, 0, stream>>>(Wcomb, bself, bcomb, biasc, L);

  // 1. CSR build (edges constant within a call)
  hipMemsetAsync(counts, 0, (size_t)N * 4, stream);
  hist_kernel<<<(E + 255) / 256, 256, 0, stream>>>(ei + E, counts, E);
  int nb = (N + 1023) / 1024;
  scan1_kernel<<<nb, 256, 0, stream>>>(counts, ex, partials, N);
  scan2_kernel<<<1, 256, 0, stream>>>(partials, nb);
  scan3_kernel<<<(N + 255) / 256, 256, 0, stream>>>(ex, partials, indptr, cursor, N, E);
  scatter_kernel<<<(E + 255) / 256, 256, 0, stream>>>(ei, cursor, ssrc, E);

  // 2. embedding: hb0 = relu(x @ Wemb^T + bemb), fused layer-0 scores -> sc0
  embed_gemm<true><<<gb, 256, 0, stream>>>(x, Wemb_b, bemb, Wscore, bscore,
                                           hbuf[0], sbuf[0], N);

  // 3. fused layers: aggr + GEMM + LN + residual (+ next scores), ping-pong
  for (int l = 0; l < L; ++l) {
    int in = l & 1, ot = (l + 1) & 1;
    if (l < L - 1) {
      fused_layer<true><<<gb, 256, 0, stream>>>(
          indptr, ssrc, sbuf[in], hbuf[in],
          Wbig + (size_t)l * 128 * 384, biasc + (size_t)l * 128,
          gamma + (size_t)l * 128, beta + (size_t)l * 128,
          Wscore + (size_t)(l + 1) * 128, bscore + (l + 1),
          hbuf[ot], sbuf[ot], N);
    } else {
      fused_layer<false><<<gb, 256, 0, stream>>>(
          indptr, ssrc, sbuf[in], hbuf[in],
          Wbig + (size_t)l * 128 * 384, biasc + (size_t)l * 128,
          gamma + (size_t)l * 128, beta + (size_t)l * 128,
          nullptr, nullptr, hbuf[ot], sbuf[ot], N);
    }
  }

  // 4. global mean pool over final state (two-stage, no atomics)
  pool_stage_kernel<<<dim3(G, PS), 128, 0, stream>>>(hbuf[L & 1], batch, pool_p, N);
  pool_final_kernel<<<(G * 128 + 255) / 256, 256, 0, stream>>>(pool_p, batch, out, N, G);
}